// Round 10
// baseline (587.110 us; speedup 1.0000x reference)
//
#include <hip/hip_runtime.h>
#include <math.h>

#define NTH 512

// broadcast lane ln (STATIC index only) of v to all lanes
__device__ __forceinline__ float rl(float v, int ln) {
  return __int_as_float(__builtin_amdgcn_readlane(__float_as_int(v), ln));
}

// acc = sum_k As[t*64+k] * v[k]; b128 with per-lane chunk rotation. t < 256.
__device__ __forceinline__ float dot64_row(const float4* __restrict__ As4,
                                           const float4* __restrict__ v4, int t) {
  float acc = 0.f;
#pragma unroll
  for (int q = 0; q < 16; ++q) {
    int qq = (q + t) & 15;
    float4 a = As4[t * 16 + qq];
    float4 b = v4[qq];
    acc = fmaf(a.x, b.x, acc); acc = fmaf(a.y, b.y, acc);
    acc = fmaf(a.z, b.z, acc); acc = fmaf(a.w, b.w, acc);
  }
  return acc;
}

// S-tile (4x4 at bi,bj) partial accumulate over c in [c0, c0+128)
__device__ __forceinline__ void fs_half(const float4* __restrict__ As4,
                                        const float4* __restrict__ wv4,
                                        int bi, int bj, int c0,
                                        float4& o0, float4& o1, float4& o2, float4& o3) {
  float a00=0,a01=0,a02=0,a03=0,a10=0,a11=0,a12=0,a13=0;
  float a20=0,a21=0,a22=0,a23=0,a30=0,a31=0,a32=0,a33=0;
  const int c40 = c0 >> 2;
  for (int c4 = c40; c4 < c40 + 32; ++c4) {
    float4 w4 = wv4[c4];
#pragma unroll
    for (int e = 0; e < 4; ++e) {
      float wc = (e==0)?w4.x:(e==1)?w4.y:(e==2)?w4.z:w4.w;
      int c = 4*c4 + e;
      float4 a4 = As4[c*16 + bi];
      float4 b4 = As4[c*16 + bj];
      float bx = b4.x*wc, by = b4.y*wc, bz = b4.z*wc, bw = b4.w*wc;
      a00=fmaf(a4.x,bx,a00); a01=fmaf(a4.x,by,a01); a02=fmaf(a4.x,bz,a02); a03=fmaf(a4.x,bw,a03);
      a10=fmaf(a4.y,bx,a10); a11=fmaf(a4.y,by,a11); a12=fmaf(a4.y,bz,a12); a13=fmaf(a4.y,bw,a13);
      a20=fmaf(a4.z,bx,a20); a21=fmaf(a4.z,by,a21); a22=fmaf(a4.z,bz,a22); a23=fmaf(a4.z,bw,a23);
      a30=fmaf(a4.w,bx,a30); a31=fmaf(a4.w,by,a31); a32=fmaf(a4.w,bz,a32); a33=fmaf(a4.w,bw,a33);
    }
  }
  o0 = make_float4(a00,a01,a02,a03);
  o1 = make_float4(a10,a11,a12,a13);
  o2 = make_float4(a20,a21,a22,a23);
  o3 = make_float4(a30,a31,a32,a33);
}

// one micro-GJ pivot among 8 register rows (runtime lane idx OK for __shfl)
#define PSTEP8(VE, V1,V2,V3,V4,V5,V6,V7, LNE) {                        \
    float piv = __shfl(VE, (LNE), 64);                                 \
    float inv = 1.0f / piv;                                            \
    VE = (lane == (LNE)) ? inv : VE * inv;                             \
    float c1 = __shfl(V1,(LNE),64); V1 = (lane==(LNE))?(-c1*inv):fmaf(-c1,VE,V1); \
    float c2 = __shfl(V2,(LNE),64); V2 = (lane==(LNE))?(-c2*inv):fmaf(-c2,VE,V2); \
    float c3 = __shfl(V3,(LNE),64); V3 = (lane==(LNE))?(-c3*inv):fmaf(-c3,VE,V3); \
    float c4_ = __shfl(V4,(LNE),64); V4 = (lane==(LNE))?(-c4_*inv):fmaf(-c4_,VE,V4); \
    float c5 = __shfl(V5,(LNE),64); V5 = (lane==(LNE))?(-c5*inv):fmaf(-c5,VE,V5); \
    float c6 = __shfl(V6,(LNE),64); V6 = (lane==(LNE))?(-c6*inv):fmaf(-c6,VE,V6); \
    float c7 = __shfl(V7,(LNE),64); V7 = (lane==(LNE))?(-c7*inv):fmaf(-c7,VE,V7); \
  }

// Pipelined blocked (rank-8) Gauss-Jordan inverse of SPD 64x64 in LDS.
// Sb padded 64x68. Wave w owns rows 8w..8w+7; lane = column. ONE barrier per
// block-step: during update-p, wave p+1 panels its updated rows in registers
// and writes them as T_{p+1}. No T/colb staging buffers. 8 waves.
__device__ __forceinline__ void gj8p(float* __restrict__ Sb, int t) {
  const int lane = t & 63, wav = t >> 6;
  // prologue: wave0 panels rows 0..7 (pivot block 0)
  if (wav == 0) {
    float v0 = Sb[0*68+lane], v1 = Sb[1*68+lane], v2 = Sb[2*68+lane], v3 = Sb[3*68+lane];
    float v4 = Sb[4*68+lane], v5 = Sb[5*68+lane], v6 = Sb[6*68+lane], v7 = Sb[7*68+lane];
    PSTEP8(v0, v1,v2,v3,v4,v5,v6,v7, 0);
    PSTEP8(v1, v0,v2,v3,v4,v5,v6,v7, 1);
    PSTEP8(v2, v0,v1,v3,v4,v5,v6,v7, 2);
    PSTEP8(v3, v0,v1,v2,v4,v5,v6,v7, 3);
    PSTEP8(v4, v0,v1,v2,v3,v5,v6,v7, 4);
    PSTEP8(v5, v0,v1,v2,v3,v4,v6,v7, 5);
    PSTEP8(v6, v0,v1,v2,v3,v4,v5,v7, 6);
    PSTEP8(v7, v0,v1,v2,v3,v4,v5,v6, 7);
    Sb[0*68+lane]=v0; Sb[1*68+lane]=v1; Sb[2*68+lane]=v2; Sb[3*68+lane]=v3;
    Sb[4*68+lane]=v4; Sb[5*68+lane]=v5; Sb[6*68+lane]=v6; Sb[7*68+lane]=v7;
  }
  __syncthreads();
  for (int p = 0; p < 8; ++p) {
    if (wav != p) {                        // wave p's rows ARE T_p: untouched
      const int prow = 8 * p;
      const int r0 = 8 * wav;
      // T_p column `lane` (rows prow..prow+7) — written last phase, 2-way free
      float t0 = Sb[(prow+0)*68+lane], t1 = Sb[(prow+1)*68+lane];
      float t2 = Sb[(prow+2)*68+lane], t3 = Sb[(prow+3)*68+lane];
      float t4 = Sb[(prow+4)*68+lane], t5 = Sb[(prow+5)*68+lane];
      float t6 = Sb[(prow+6)*68+lane], t7 = Sb[(prow+7)*68+lane];
      const bool pivc = (lane >= prow) && (lane < prow + 8);
      // own-row current values (0-base on pivot cols)
      float m0 = pivc ? 0.f : Sb[(r0+0)*68+lane];
      float m1 = pivc ? 0.f : Sb[(r0+1)*68+lane];
      float m2 = pivc ? 0.f : Sb[(r0+2)*68+lane];
      float m3 = pivc ? 0.f : Sb[(r0+3)*68+lane];
      float m4 = pivc ? 0.f : Sb[(r0+4)*68+lane];
      float m5 = pivc ? 0.f : Sb[(r0+5)*68+lane];
      float m6 = pivc ? 0.f : Sb[(r0+6)*68+lane];
      float m7 = pivc ? 0.f : Sb[(r0+7)*68+lane];
      // C rows (wave-uniform float4 broadcasts) + rank-8 update
#define GJUPD(MR, RR) {                                                    \
        const float4* cp = (const float4*)&Sb[(r0+(RR))*68 + prow];        \
        float4 cA = cp[0], cB = cp[1];                                     \
        MR -= cA.x*t0 + cA.y*t1 + cA.z*t2 + cA.w*t3                        \
            + cB.x*t4 + cB.y*t5 + cB.z*t6 + cB.w*t7;                       \
      }
      GJUPD(m0,0) GJUPD(m1,1) GJUPD(m2,2) GJUPD(m3,3)
      GJUPD(m4,4) GJUPD(m5,5) GJUPD(m6,6) GJUPD(m7,7)
#undef GJUPD
      if (p < 7 && wav == p + 1) {         // panel next pivot block in-register
        const int pb = 8 * (p + 1);
        PSTEP8(m0, m1,m2,m3,m4,m5,m6,m7, pb+0);
        PSTEP8(m1, m0,m2,m3,m4,m5,m6,m7, pb+1);
        PSTEP8(m2, m0,m1,m3,m4,m5,m6,m7, pb+2);
        PSTEP8(m3, m0,m1,m2,m4,m5,m6,m7, pb+3);
        PSTEP8(m4, m0,m1,m2,m3,m5,m6,m7, pb+4);
        PSTEP8(m5, m0,m1,m2,m3,m4,m6,m7, pb+5);
        PSTEP8(m6, m0,m1,m2,m3,m4,m5,m7, pb+6);
        PSTEP8(m7, m0,m1,m2,m3,m4,m5,m6, pb+7);
      }
      Sb[(r0+0)*68+lane]=m0; Sb[(r0+1)*68+lane]=m1;
      Sb[(r0+2)*68+lane]=m2; Sb[(r0+3)*68+lane]=m3;
      Sb[(r0+4)*68+lane]=m4; Sb[(r0+5)*68+lane]=m5;
      Sb[(r0+6)*68+lane]=m6; Sb[(r0+7)*68+lane]=m7;
    }
    __syncthreads();
  }
}

// out_lane = sum_j Sinv[t][j]*rh[j]; rh one value per lane of wave0. t < 64.
__device__ __forceinline__ float matS_lds(const float* __restrict__ Sb, float rh, int t) {
  const float4* Sb4 = (const float4*)Sb;
  float acc = 0.f;
#pragma unroll
  for (int m = 0; m < 16; ++m) {
    float4 s4 = Sb4[t*17 + m];
    acc = fmaf(s4.x, rl(rh, 4*m+0), acc);
    acc = fmaf(s4.y, rl(rh, 4*m+1), acc);
    acc = fmaf(s4.z, rl(rh, 4*m+2), acc);
    acc = fmaf(s4.w, rl(rh, 4*m+3), acc);
  }
  return acc;
}

__global__ __launch_bounds__(NTH, 1)
void optnet_kernel(const float* __restrict__ x,  const float* __restrict__ W1,
                   const float* __restrict__ b1, const float* __restrict__ W2,
                   const float* __restrict__ b2, const float* __restrict__ A,
                   float* __restrict__ out)
{
  extern __shared__ float sm[];
  const int b = blockIdx.x;
  const int t = threadIdx.x;
  const int lane = t & 63;
  const int wav = t >> 6;
  const bool owner = (t < 256);

  float* As    = sm;               // 16384: A^T c-major, As[c*64+k] = A[k][c]
  float* Sb    = sm + 16384;       // 4352:  S / Sinv, padded rows (64x68)
  float* xld   = Sb;               // alias (first 1024) during h-compute
  float* Pbuf  = sm + 20736;       // 2176: form_S second-half partials (136x16)
  float* h     = Pbuf + 2176;      // 256
  float* z     = h + 256;          // 256
  float* wHd   = z + 256;          // 256: 1/Hd
  float* wtp   = wHd + 256;        // 256: top/Hd
  float* partA = wtp + 256;        // 192: re partials (3 groups) / logits
  float* partB = partA + 192;      // 192: A@wtp partials (3 groups)
  float* partB2= partB + 192;      // 512: corrector A@wtp partials (8 groups)
  float* nu    = partB2 + 512;     // 64
  float* rev   = nu + 64;          // 64
  float* dnu   = rev + 64;         // 64
  float* red   = dnu + 64;         // 16

  const float4* As4  = (const float4*)As;
  float4*       Sb4  = (float4*)Sb;
  const float4* wv4  = (const float4*)wHd;
  const float4* nu4  = (const float4*)nu;
  const float4* dnu4 = (const float4*)dnu;
  float4*       Pb4  = (float4*)Pbuf;

  // upper-triangular 4x4 tile map for form_S halves (t < 272)
  int bi = 0, bj = 0;
  if (t < 272) {
    int rr = (t < 136) ? t : (t - 136);
    while (rr >= 16 - bi) { rr -= 16 - bi; ++bi; }
    bj = bi + rr;
  }
  // helper partial-group c-ranges (threads 272..463): groups of 64 lanes
  const int pg  = (t - 272) >> 6;            // 0..2 when in range
  const int plo = pg * 85 + (pg > 0 ? 1 : 0);
  const int phi = plo + 85 + (pg == 0 ? 1 : 0);

  // ---- stage A^T (c-major) and x row ----
  for (int g = t; g < 64 * 256; g += NTH)
    As[(g & 255) * 64 + (g >> 8)] = A[g];
  for (int g = t; g < 1024; g += NTH)
    xld[g] = x[b * 1024 + g];
  __syncthreads();

  // ---- h = relu(x @ W1^T + b1): 8 waves x 32 outputs ----
  {
    const float4* xr = (const float4*)xld;
    for (int jj = 0; jj < 32; ++jj) {
      int j = (wav << 5) + jj;
      const float4* w1r = (const float4*)(W1 + (size_t)j * 1024);
      float acc = 0.f;
#pragma unroll
      for (int mm = 0; mm < 4; ++mm) {
        float4 a = w1r[lane + (mm << 6)];
        float4 xv = xr[lane + (mm << 6)];
        acc = fmaf(a.x,xv.x,fmaf(a.y,xv.y,fmaf(a.z,xv.z,fmaf(a.w,xv.w,acc))));
      }
#pragma unroll
      for (int off = 32; off > 0; off >>= 1) acc += __shfl_xor(acc, off, 64);
      if (lane == 0) { float v = acc + b1[j]; h[j] = v > 0.f ? v : 0.f; }
    }
  }
  __syncthreads();
  const float hr = h[t & 255];

  // ---- initial solve: Hd = QPEN -> S0 = 10*A*A^T ----
  if (owner) { wHd[t] = 10.0f; wtp[t] = hr * 10.0f; }
  __syncthreads();
  float4 o0, o1, o2, o3;
  if (t < 272) {
    fs_half(As4, wv4, bi, bj, (t < 136) ? 0 : 128, o0, o1, o2, o3);
    if (t >= 136) {
      int tt = t - 136;
      Pb4[tt*4+0]=o0; Pb4[tt*4+1]=o1; Pb4[tt*4+2]=o2; Pb4[tt*4+3]=o3;
    }
  } else if (t < 464) {                    // A @ (h/QPEN) partials
    float accB = 0.f;
    for (int c = plo; c < phi; ++c)
      accB = fmaf(wtp[c], As[c * 64 + lane], accB);
    partB[pg * 64 + lane] = accB;
  }
  __syncthreads();
  if (t < 136) {                           // combine + write S (+ mirror)
    float4 p0=Pb4[t*4+0], p1=Pb4[t*4+1], p2=Pb4[t*4+2], p3=Pb4[t*4+3];
    o0.x+=p0.x; o0.y+=p0.y; o0.z+=p0.z; o0.w+=p0.w;
    o1.x+=p1.x; o1.y+=p1.y; o1.z+=p1.z; o1.w+=p1.w;
    o2.x+=p2.x; o2.y+=p2.y; o2.z+=p2.z; o2.w+=p2.w;
    o3.x+=p3.x; o3.y+=p3.y; o3.z+=p3.z; o3.w+=p3.w;
    Sb4[(4*bi+0)*17 + bj] = o0;
    Sb4[(4*bi+1)*17 + bj] = o1;
    Sb4[(4*bi+2)*17 + bj] = o2;
    Sb4[(4*bi+3)*17 + bj] = o3;
    if (bi != bj) {
      Sb4[(4*bj+0)*17 + bi] = make_float4(o0.x,o1.x,o2.x,o3.x);
      Sb4[(4*bj+1)*17 + bi] = make_float4(o0.y,o1.y,o2.y,o3.y);
      Sb4[(4*bj+2)*17 + bi] = make_float4(o0.z,o1.z,o2.z,o3.z);
      Sb4[(4*bj+3)*17 + bi] = make_float4(o0.w,o1.w,o2.w,o3.w);
    }
  }
  __syncthreads();
  gj8p(Sb, t);                             // Sb <- Sinv (ends with barrier)
  if (t < 64) {
    float rh = partB[t] + partB[64 + t] + partB[128 + t] - 1.0f;
    nu[t] = matS_lds(Sb, rh, t);
  }
  __syncthreads();

  float zt = 0.f, st = 0.f, lt = 0.f;
  if (owner) {
    float atd = dot64_row(As4, nu4, t);    // (A^T nu)_t
    zt = (hr - atd) * 10.0f;
    z[t] = zt;
    st = fmaxf(zt, 1.0f);
    lt = 1.0f;
  }
  __syncthreads();

  // ---- 12 predictor-corrector IP iterations ----
  float rit = 0.f, Dt = 0.f, wt = 0.f, g1 = 0.f, top1 = 0.f, rxt = 0.f;
  for (int it = 0; it < 12; ++it) {
    if (owner) {
      const float nuA = dot64_row(As4, nu4, t);    // (nu @ A)_t
      rxt = 0.1f * zt - hr - lt + nuA;             // p = -h
      rit = st - zt;
      Dt  = lt / st;
      wt  = 1.0f / (0.1f + Dt);
      const float rs1 = lt * st;
      g1  = (lt * rit - rs1) / st;
      top1 = -rxt + g1;
      wHd[t] = wt;
      wtp[t] = top1 * wt;
    }
    __syncthreads();                               // wHd, wtp ready
    if (t < 272) {                                 // form_S halves
      fs_half(As4, wv4, bi, bj, (t < 136) ? 0 : 128, o0, o1, o2, o3);
      if (t >= 136) {
        int tt = t - 136;
        Pb4[tt*4+0]=o0; Pb4[tt*4+1]=o1; Pb4[tt*4+2]=o2; Pb4[tt*4+3]=o3;
      }
    } else if (t < 464) {                          // re + A@wtp partials
      float accA = 0.f, accB = 0.f;
      for (int c = plo; c < phi; ++c) {
        float av = As[c * 64 + lane];
        accA = fmaf(z[c],   av, accA);
        accB = fmaf(wtp[c], av, accB);
      }
      partA[pg * 64 + lane] = accA;
      partB[pg * 64 + lane] = accB;
    }
    __syncthreads();
    if (t < 136) {                                 // combine + write S
      float4 p0=Pb4[t*4+0], p1=Pb4[t*4+1], p2=Pb4[t*4+2], p3=Pb4[t*4+3];
      o0.x+=p0.x; o0.y+=p0.y; o0.z+=p0.z; o0.w+=p0.w;
      o1.x+=p1.x; o1.y+=p1.y; o1.z+=p1.z; o1.w+=p1.w;
      o2.x+=p2.x; o2.y+=p2.y; o2.z+=p2.z; o2.w+=p2.w;
      o3.x+=p3.x; o3.y+=p3.y; o3.z+=p3.z; o3.w+=p3.w;
      Sb4[(4*bi+0)*17 + bj] = o0;
      Sb4[(4*bi+1)*17 + bj] = o1;
      Sb4[(4*bi+2)*17 + bj] = o2;
      Sb4[(4*bi+3)*17 + bj] = o3;
      if (bi != bj) {
        Sb4[(4*bj+0)*17 + bi] = make_float4(o0.x,o1.x,o2.x,o3.x);
        Sb4[(4*bj+1)*17 + bi] = make_float4(o0.y,o1.y,o2.y,o3.y);
        Sb4[(4*bj+2)*17 + bi] = make_float4(o0.z,o1.z,o2.z,o3.z);
        Sb4[(4*bj+3)*17 + bi] = make_float4(o0.w,o1.w,o2.w,o3.w);
      }
    }
    __syncthreads();
    gj8p(Sb, t);                                   // Sb <- Sinv
    if (t < 64) {
      float re_t = partA[t] + partA[64 + t] + partA[128 + t] - 1.0f;
      rev[t] = re_t;
      float rh = partB[t] + partB[64 + t] + partB[128 + t] + re_t;
      dnu[t] = matS_lds(Sb, rh, t);
    }
    __syncthreads();                               // dnu, rev ready
    float dsa = 0.f, dla = 0.f;
    if (owner) {                                   // affine dir + FUSED reduce
      float atd = dot64_row(As4, dnu4, t);
      float dza = (top1 - atd) * wt;
      dsa = dza - rit;
      dla = g1 - Dt * dza;
      float r1 = dsa < 0.f ? -st / dsa : 1e10f;
      float r2 = dla < 0.f ? -lt / dla : 1e10f;
      float mn = fminf(r1, r2);
      float q0 = st * lt;                          // mu_aff polynomial sums:
      float q1 = st * dla + dsa * lt;              // p2(a)=q0 + a q1 + a^2 q2
      float q2 = dsa * dla;
#pragma unroll
      for (int off = 32; off > 0; off >>= 1) {
        mn = fminf(mn, __shfl_xor(mn, off, 64));
        q0 += __shfl_xor(q0, off, 64);
        q1 += __shfl_xor(q1, off, 64);
        q2 += __shfl_xor(q2, off, 64);
      }
      if (lane == 0) {
        red[wav] = mn; red[4+wav] = q0; red[8+wav] = q1; red[12+wav] = q2;
      }
    }
    __syncthreads();
    if (owner) {                                   // sigma + corrector rhs prep
      const float a_aff = fminf(1.0f, 0.999f * fminf(fminf(red[0],red[1]), fminf(red[2],red[3])));
      const float S0 = red[4] + red[5] + red[6] + red[7];
      const float S1 = red[8] + red[9] + red[10] + red[11];
      const float S2 = red[12] + red[13] + red[14] + red[15];
      const float mu  = S0 * (1.0f / 256.0f);
      const float mua = (S0 + a_aff * S1 + a_aff * a_aff * S2) * (1.0f / 256.0f);
      float sig = mua / mu; sig = sig * sig * sig;
      const float smu = sig * mu;
      const float rs2 = lt * st + dsa * dla - smu;
      const float g2  = (lt * rit - rs2) / st;
      const float top2 = -rxt + g2;
      wtp[t] = top2 * wt;
    }
    __syncthreads();                               // wtp2 ready
    {                                              // corrector A@wtp: 8 groups
      float accB = 0.f;
      for (int cc = 0; cc < 32; ++cc) {
        int c = (wav << 5) + cc;
        accB = fmaf(wtp[c], As[c * 64 + lane], accB);
      }
      partB2[t] = accB;
    }
    __syncthreads();
    if (t < 64) {
      float rh = partB2[t] + partB2[64+t] + partB2[128+t] + partB2[192+t]
               + partB2[256+t] + partB2[320+t] + partB2[384+t] + partB2[448+t]
               + rev[t];
      dnu[t] = matS_lds(Sb, rh, t);
    }
    __syncthreads();
    float ds2 = 0.f, dl2 = 0.f, dz2 = 0.f;
    if (owner) {
      float atd = dot64_row(As4, dnu4, t);
      const float top2 = wtp[t] / wt;              // recover top2
      dz2 = (top2 - atd) * wt;
      ds2 = dz2 - rit;
      dl2 = (top2 + rxt) - Dt * dz2;               // g2 = top2 + rxt
      float r1 = ds2 < 0.f ? -st / ds2 : 1e10f;
      float r2 = dl2 < 0.f ? -lt / dl2 : 1e10f;
      float mn = fminf(r1, r2);
#pragma unroll
      for (int off = 32; off > 0; off >>= 1) mn = fminf(mn, __shfl_xor(mn, off, 64));
      if (lane == 0) red[wav] = mn;
    }
    __syncthreads();
    if (owner) {
      const float a = fminf(1.0f, 0.999f * fminf(fminf(red[0],red[1]), fminf(red[2],red[3])));
      zt += a * dz2;
      st = fmaxf(st + a * ds2, 1e-8f);
      lt = fmaxf(lt + a * dl2, 1e-8f);
      z[t] = zt;
      if (t < 64) nu[t] += a * dnu[t];
    }
    __syncthreads();
  }

  // ---- logits = z @ W2^T + b2 ; log_softmax ----
  if (t < 160) {
    int cls = t >> 4, pp = t & 15;
    float acc = 0.f;
#pragma unroll
    for (int e = 0; e < 16; ++e) {
      int c = (pp << 4) + e;
      acc = fmaf(z[c], W2[cls * 256 + c], acc);
    }
    partA[t] = acc;
  }
  __syncthreads();
  if (t < 10) {
    float s = b2[t];
#pragma unroll
    for (int pp = 0; pp < 16; ++pp) s += partA[(t << 4) + pp];
    red[t] = s;
  }
  __syncthreads();
  if (t == 0) {
    float mx = red[0];
#pragma unroll
    for (int c = 1; c < 10; ++c) mx = fmaxf(mx, red[c]);
    float se = 0.f;
#pragma unroll
    for (int c = 0; c < 10; ++c) se += expf(red[c] - mx);
    float lse = mx + logf(se);
    for (int c = 0; c < 10; ++c) out[b * 10 + c] = red[c] - lse;
  }
}

extern "C" void kernel_launch(void* const* d_in, const int* in_sizes, int n_in,
                              void* d_out, int out_size, void* d_ws, size_t ws_size,
                              hipStream_t stream) {
  (void)in_sizes; (void)n_in; (void)out_size; (void)d_ws; (void)ws_size;
  const float* x  = (const float*)d_in[0];
  const float* W1 = (const float*)d_in[1];
  const float* b1 = (const float*)d_in[2];
  const float* W2 = (const float*)d_in[3];
  const float* b2 = (const float*)d_in[4];
  const float* A  = (const float*)d_in[5];
  float* out = (float*)d_out;

  // floats: As 16384 + Sb 4352 + Pbuf 2176 + (h,z,wHd,wtp)=4*256
  //         + partA 192 + partB 192 + partB2 512 + 3*64 + 16  = 25040
  const size_t shmem = (16384 + 4352 + 2176 + 4*256 + 192 + 192 + 512 + 3*64 + 16)
                       * sizeof(float);   // 100160 B
  (void)hipFuncSetAttribute((const void*)optnet_kernel,
                            hipFuncAttributeMaxDynamicSharedMemorySize, (int)shmem);
  optnet_kernel<<<128, NTH, shmem, stream>>>(x, W1, b1, W2, b2, A, out);
}

// Round 14
// 485.252 us; speedup vs baseline: 1.2099x; 1.2099x over previous
//
#include <hip/hip_runtime.h>
#include <math.h>

#define NTH 512

// broadcast lane ln (STATIC index only) of v to all lanes
__device__ __forceinline__ float rl(float v, int ln) {
  return __int_as_float(__builtin_amdgcn_readlane(__float_as_int(v), ln));
}

// acc = sum_k As[t*64+k] * v[k]; b128 with per-lane chunk rotation. t < 256.
__device__ __forceinline__ float dot64_row(const float4* __restrict__ As4,
                                           const float4* __restrict__ v4, int t) {
  float acc = 0.f;
#pragma unroll
  for (int q = 0; q < 16; ++q) {
    int qq = (q + t) & 15;
    float4 a = As4[t * 16 + qq];
    float4 b = v4[qq];
    acc = fmaf(a.x, b.x, acc); acc = fmaf(a.y, b.y, acc);
    acc = fmaf(a.z, b.z, acc); acc = fmaf(a.w, b.w, acc);
  }
  return acc;
}

// S-tile (4x4 at bi,bj) partial accumulate over c in [c0, c0+128)
__device__ __forceinline__ void fs_half(const float4* __restrict__ As4,
                                        const float4* __restrict__ wv4,
                                        int bi, int bj, int c0,
                                        float4& o0, float4& o1, float4& o2, float4& o3) {
  float a00=0,a01=0,a02=0,a03=0,a10=0,a11=0,a12=0,a13=0;
  float a20=0,a21=0,a22=0,a23=0,a30=0,a31=0,a32=0,a33=0;
  const int c40 = c0 >> 2;
  for (int c4 = c40; c4 < c40 + 32; ++c4) {
    float4 w4 = wv4[c4];
#pragma unroll
    for (int e = 0; e < 4; ++e) {
      float wc = (e==0)?w4.x:(e==1)?w4.y:(e==2)?w4.z:w4.w;
      int c = 4*c4 + e;
      float4 a4 = As4[c*16 + bi];
      float4 b4 = As4[c*16 + bj];
      float bx = b4.x*wc, by = b4.y*wc, bz = b4.z*wc, bw = b4.w*wc;
      a00=fmaf(a4.x,bx,a00); a01=fmaf(a4.x,by,a01); a02=fmaf(a4.x,bz,a02); a03=fmaf(a4.x,bw,a03);
      a10=fmaf(a4.y,bx,a10); a11=fmaf(a4.y,by,a11); a12=fmaf(a4.y,bz,a12); a13=fmaf(a4.y,bw,a13);
      a20=fmaf(a4.z,bx,a20); a21=fmaf(a4.z,by,a21); a22=fmaf(a4.z,bz,a22); a23=fmaf(a4.z,bw,a23);
      a30=fmaf(a4.w,bx,a30); a31=fmaf(a4.w,by,a31); a32=fmaf(a4.w,bz,a32); a33=fmaf(a4.w,bw,a33);
    }
  }
  o0 = make_float4(a00,a01,a02,a03);
  o1 = make_float4(a10,a11,a12,a13);
  o2 = make_float4(a20,a21,a22,a23);
  o3 = make_float4(a30,a31,a32,a33);
}

// one micro-GJ pivot within the 8-row panel (wave0 regs, runtime lane idx OK)
#define PSTEP8(VE, V1,V2,V3,V4,V5,V6,V7, LNE) {                        \
    float piv = __shfl(VE, (LNE), 64);                                 \
    float inv = 1.0f / piv;                                            \
    VE = (lane == (LNE)) ? inv : VE * inv;                             \
    float c1 = __shfl(V1,(LNE),64); V1 = (lane==(LNE))?(-c1*inv):fmaf(-c1,VE,V1); \
    float c2 = __shfl(V2,(LNE),64); V2 = (lane==(LNE))?(-c2*inv):fmaf(-c2,VE,V2); \
    float c3 = __shfl(V3,(LNE),64); V3 = (lane==(LNE))?(-c3*inv):fmaf(-c3,VE,V3); \
    float c4_ = __shfl(V4,(LNE),64); V4 = (lane==(LNE))?(-c4_*inv):fmaf(-c4_,VE,V4); \
    float c5 = __shfl(V5,(LNE),64); V5 = (lane==(LNE))?(-c5*inv):fmaf(-c5,VE,V5); \
    float c6 = __shfl(V6,(LNE),64); V6 = (lane==(LNE))?(-c6*inv):fmaf(-c6,VE,V6); \
    float c7 = __shfl(V7,(LNE),64); V7 = (lane==(LNE))?(-c7*inv):fmaf(-c7,VE,V7); \
  }

// R8's proven blocked (rank-8) Gauss-Jordan inverse of SPD 64x64 in LDS.
// Sb: padded 64x68. T: 8x64. colb: 2x64 float4 planes. 8 waves. No spill.
__device__ __forceinline__ void gj8(float* __restrict__ Sb, float* __restrict__ T,
                                    float* __restrict__ colb, int t) {
  float4* Sb4 = (float4*)Sb;
  float4* T4 = (float4*)T;
  float4* colb4 = (float4*)colb;
  const int lane = t & 63, wav = t >> 6;
  for (int p = 0; p < 8; ++p) {
    if (wav == 0) {                        // panel rows 8p..8p+7, lane = column
      float v0 = Sb[(8*p+0)*68 + lane];
      float v1 = Sb[(8*p+1)*68 + lane];
      float v2 = Sb[(8*p+2)*68 + lane];
      float v3 = Sb[(8*p+3)*68 + lane];
      float v4 = Sb[(8*p+4)*68 + lane];
      float v5 = Sb[(8*p+5)*68 + lane];
      float v6 = Sb[(8*p+6)*68 + lane];
      float v7 = Sb[(8*p+7)*68 + lane];
      PSTEP8(v0, v1,v2,v3,v4,v5,v6,v7, 8*p+0);
      PSTEP8(v1, v0,v2,v3,v4,v5,v6,v7, 8*p+1);
      PSTEP8(v2, v0,v1,v3,v4,v5,v6,v7, 8*p+2);
      PSTEP8(v3, v0,v1,v2,v4,v5,v6,v7, 8*p+3);
      PSTEP8(v4, v0,v1,v2,v3,v5,v6,v7, 8*p+4);
      PSTEP8(v5, v0,v1,v2,v3,v4,v6,v7, 8*p+5);
      PSTEP8(v6, v0,v1,v2,v3,v4,v5,v7, 8*p+6);
      PSTEP8(v7, v0,v1,v2,v3,v4,v5,v6, 8*p+7);
      T[0*64+lane]=v0; T[1*64+lane]=v1; T[2*64+lane]=v2; T[3*64+lane]=v3;
      T[4*64+lane]=v4; T[5*64+lane]=v5; T[6*64+lane]=v6; T[7*64+lane]=v7;
    } else if (wav == 1) {                 // stage pre-update pivot col chunks
      colb4[lane]      = *(const float4*)&Sb[lane*68 + 8*p];
      colb4[64 + lane] = *(const float4*)&Sb[lane*68 + 8*p + 4];
    }
    __syncthreads();                       // T, colb ready
    float4 cA = colb4[lane];
    float4 cB = colb4[64 + lane];
    const bool rowsJ = ((lane >> 3) == p);
    const int e = lane & 7;
#pragma unroll
    for (int q = 0; q < 2; ++q) {
      const int c = 2*wav + q;
      if (rowsJ) {                         // panel rows <- T
        Sb4[lane*17 + c] = T4[e*16 + c];
      } else {                             // rank-8 update; pivot cols via zero-base
        float4 t0=T4[0*16+c], t1=T4[1*16+c], t2=T4[2*16+c], t3=T4[3*16+c];
        float4 t4=T4[4*16+c], t5=T4[5*16+c], t6=T4[6*16+c], t7=T4[7*16+c];
        float4 mv;
        if (c == 2*p || c == 2*p+1) { mv = make_float4(0.f,0.f,0.f,0.f); }
        else mv = Sb4[lane*17 + c];
        mv.x -= cA.x*t0.x + cA.y*t1.x + cA.z*t2.x + cA.w*t3.x
              + cB.x*t4.x + cB.y*t5.x + cB.z*t6.x + cB.w*t7.x;
        mv.y -= cA.x*t0.y + cA.y*t1.y + cA.z*t2.y + cA.w*t3.y
              + cB.x*t4.y + cB.y*t5.y + cB.z*t6.y + cB.w*t7.y;
        mv.z -= cA.x*t0.z + cA.y*t1.z + cA.z*t2.z + cA.w*t3.z
              + cB.x*t4.z + cB.y*t5.z + cB.z*t6.z + cB.w*t7.z;
        mv.w -= cA.x*t0.w + cA.y*t1.w + cA.z*t2.w + cA.w*t3.w
              + cB.x*t4.w + cB.y*t5.w + cB.z*t6.w + cB.w*t7.w;
        Sb4[lane*17 + c] = mv;
      }
    }
    __syncthreads();
  }
}

// out_lane = sum_j Sinv[t][j]*rh[j]; rh one value per lane of wave0. t < 64.
__device__ __forceinline__ float matS_lds(const float* __restrict__ Sb, float rh, int t) {
  const float4* Sb4 = (const float4*)Sb;
  float acc = 0.f;
#pragma unroll
  for (int m = 0; m < 16; ++m) {
    float4 s4 = Sb4[t*17 + m];
    acc = fmaf(s4.x, rl(rh, 4*m+0), acc);
    acc = fmaf(s4.y, rl(rh, 4*m+1), acc);
    acc = fmaf(s4.z, rl(rh, 4*m+2), acc);
    acc = fmaf(s4.w, rl(rh, 4*m+3), acc);
  }
  return acc;
}

__global__ __launch_bounds__(NTH, 1)
void optnet_kernel(const float* __restrict__ x,  const float* __restrict__ W1,
                   const float* __restrict__ b1, const float* __restrict__ W2,
                   const float* __restrict__ b2, const float* __restrict__ A,
                   float* __restrict__ out)
{
  extern __shared__ float sm[];
  const int b = blockIdx.x;
  const int t = threadIdx.x;
  const int lane = t & 63;
  const int wav = t >> 6;
  const bool owner = (t < 256);

  float* As    = sm;               // 16384: A^T c-major, As[c*64+k] = A[k][c]
  float* Sb    = sm + 16384;       // 4352:  S / Sinv, padded rows (64x68)
  float* xld   = Sb;               // alias (first 1024) during h-compute
  float* Pbuf  = sm + 20736;       // 2176: form_S second-half partials (136x16)
  float* T     = Pbuf + 2176;      // 512: GJ panel (8x64)
  float* colb  = T + 512;          // 512: GJ pivot col chunks (2x64 f4)
  float* h     = colb + 512;       // 256
  float* z     = h + 256;          // 256
  float* wHd   = z + 256;          // 256: 1/Hd
  float* wtp   = wHd + 256;        // 256: top/Hd
  float* partA = wtp + 256;        // 192: re partials (3 groups) / logits
  float* partB = partA + 192;      // 192: A@wtp partials (3 groups)
  float* partB2= partB + 192;      // 512: corrector A@wtp partials (8 groups)
  float* nu    = partB2 + 512;     // 64 (pre-loop only)
  float* rev   = nu + 64;          // 64
  float* dnu   = rev + 64;         // 64
  float* red   = dnu + 64;         // 16

  const float4* As4  = (const float4*)As;
  float4*       Sb4  = (float4*)Sb;
  const float4* wv4  = (const float4*)wHd;
  const float4* nu4  = (const float4*)nu;
  const float4* dnu4 = (const float4*)dnu;
  float4*       Pb4  = (float4*)Pbuf;

  // upper-triangular 4x4 tile map for form_S halves (t < 272)
  int bi = 0, bj = 0;
  if (t < 272) {
    int rr = (t < 136) ? t : (t - 136);
    while (rr >= 16 - bi) { rr -= 16 - bi; ++bi; }
    bj = bi + rr;
  }
  // helper partial-group c-ranges (threads 272..463): groups of 64 lanes
  const int pg  = (t - 272) >> 6;            // 0..2 when in range
  const int plo = pg * 85 + (pg > 0 ? 1 : 0);
  const int phi = plo + 85 + (pg == 0 ? 1 : 0);

  // ---- stage A^T (c-major) and x row ----
  for (int g = t; g < 64 * 256; g += NTH)
    As[(g & 255) * 64 + (g >> 8)] = A[g];
  for (int g = t; g < 1024; g += NTH)
    xld[g] = x[b * 1024 + g];
  __syncthreads();

  // ---- h = relu(x @ W1^T + b1): 8 waves x 32 outputs ----
  {
    const float4* xr = (const float4*)xld;
    for (int jj = 0; jj < 32; ++jj) {
      int j = (wav << 5) + jj;
      const float4* w1r = (const float4*)(W1 + (size_t)j * 1024);
      float acc = 0.f;
#pragma unroll
      for (int mm = 0; mm < 4; ++mm) {
        float4 a = w1r[lane + (mm << 6)];
        float4 xv = xr[lane + (mm << 6)];
        acc = fmaf(a.x,xv.x,fmaf(a.y,xv.y,fmaf(a.z,xv.z,fmaf(a.w,xv.w,acc))));
      }
#pragma unroll
      for (int off = 32; off > 0; off >>= 1) acc += __shfl_xor(acc, off, 64);
      if (lane == 0) { float v = acc + b1[j]; h[j] = v > 0.f ? v : 0.f; }
    }
  }
  __syncthreads();
  const float hr = h[t & 255];

  // ---- initial solve: Hd = QPEN -> S0 = 10*A*A^T ----
  if (owner) { wHd[t] = 10.0f; wtp[t] = hr * 10.0f; }
  __syncthreads();
  float4 o0, o1, o2, o3;
  if (t < 272) {
    fs_half(As4, wv4, bi, bj, (t < 136) ? 0 : 128, o0, o1, o2, o3);
    if (t >= 136) {
      int tt = t - 136;
      Pb4[tt*4+0]=o0; Pb4[tt*4+1]=o1; Pb4[tt*4+2]=o2; Pb4[tt*4+3]=o3;
    }
  } else if (t < 464) {                    // A @ (h/QPEN) partials
    float accB = 0.f;
    for (int c = plo; c < phi; ++c)
      accB = fmaf(wtp[c], As[c * 64 + lane], accB);
    partB[pg * 64 + lane] = accB;
  }
  __syncthreads();
  if (t < 136) {                           // combine + write S (+ mirror)
    float4 p0=Pb4[t*4+0], p1=Pb4[t*4+1], p2=Pb4[t*4+2], p3=Pb4[t*4+3];
    o0.x+=p0.x; o0.y+=p0.y; o0.z+=p0.z; o0.w+=p0.w;
    o1.x+=p1.x; o1.y+=p1.y; o1.z+=p1.z; o1.w+=p1.w;
    o2.x+=p2.x; o2.y+=p2.y; o2.z+=p2.z; o2.w+=p2.w;
    o3.x+=p3.x; o3.y+=p3.y; o3.z+=p3.z; o3.w+=p3.w;
    Sb4[(4*bi+0)*17 + bj] = o0;
    Sb4[(4*bi+1)*17 + bj] = o1;
    Sb4[(4*bi+2)*17 + bj] = o2;
    Sb4[(4*bi+3)*17 + bj] = o3;
    if (bi != bj) {
      Sb4[(4*bj+0)*17 + bi] = make_float4(o0.x,o1.x,o2.x,o3.x);
      Sb4[(4*bj+1)*17 + bi] = make_float4(o0.y,o1.y,o2.y,o3.y);
      Sb4[(4*bj+2)*17 + bi] = make_float4(o0.z,o1.z,o2.z,o3.z);
      Sb4[(4*bj+3)*17 + bi] = make_float4(o0.w,o1.w,o2.w,o3.w);
    }
  }
  __syncthreads();
  gj8(Sb, T, colb, t);                     // Sb <- Sinv (ends with barrier)
  if (t < 64) {
    float rh = partB[t] + partB[64 + t] + partB[128 + t] - 1.0f;
    nu[t] = matS_lds(Sb, rh, t);
  }
  __syncthreads();

  // z0 + iteration-0 prep (nuA carried in-register from here on)
  float zt = 0.f, st = 0.f, lt = 0.f, nuA = 0.f;
  float rxt = 0.f, rit = 0.f, Dt = 0.f, wt = 0.f, g1 = 0.f, top1 = 0.f;
  if (owner) {
    nuA = dot64_row(As4, nu4, t);          // (nu @ A)_t
    zt = (hr - nuA) * 10.0f;
    z[t] = zt;
    st = fmaxf(zt, 1.0f);
    lt = 1.0f;
    rxt = 0.1f * zt - hr - lt + nuA;
    rit = st - zt;
    Dt  = lt / st;
    wt  = 1.0f / (0.1f + Dt);
    g1  = -Dt * zt;                        // (lt*rit - lt*st)/st
    top1 = -rxt + g1;
    wHd[t] = wt;
    wtp[t] = top1 * wt;
  }
  __syncthreads();

  // ---- 12 predictor-corrector IP iterations ----
  for (int it = 0; it < 12; ++it) {
    // a: form_S halves + re/A@wtp partials (concurrent)
    if (t < 272) {
      fs_half(As4, wv4, bi, bj, (t < 136) ? 0 : 128, o0, o1, o2, o3);
      if (t >= 136) {
        int tt = t - 136;
        Pb4[tt*4+0]=o0; Pb4[tt*4+1]=o1; Pb4[tt*4+2]=o2; Pb4[tt*4+3]=o3;
      }
    } else if (t < 464) {
      float accA = 0.f, accB = 0.f;
      for (int c = plo; c < phi; ++c) {
        float av = As[c * 64 + lane];
        accA = fmaf(z[c],   av, accA);
        accB = fmaf(wtp[c], av, accB);
      }
      partA[pg * 64 + lane] = accA;
      partB[pg * 64 + lane] = accB;
    }
    __syncthreads();
    // b: combine + write S
    if (t < 136) {
      float4 p0=Pb4[t*4+0], p1=Pb4[t*4+1], p2=Pb4[t*4+2], p3=Pb4[t*4+3];
      o0.x+=p0.x; o0.y+=p0.y; o0.z+=p0.z; o0.w+=p0.w;
      o1.x+=p1.x; o1.y+=p1.y; o1.z+=p1.z; o1.w+=p1.w;
      o2.x+=p2.x; o2.y+=p2.y; o2.z+=p2.z; o2.w+=p2.w;
      o3.x+=p3.x; o3.y+=p3.y; o3.z+=p3.z; o3.w+=p3.w;
      Sb4[(4*bi+0)*17 + bj] = o0;
      Sb4[(4*bi+1)*17 + bj] = o1;
      Sb4[(4*bi+2)*17 + bj] = o2;
      Sb4[(4*bi+3)*17 + bj] = o3;
      if (bi != bj) {
        Sb4[(4*bj+0)*17 + bi] = make_float4(o0.x,o1.x,o2.x,o3.x);
        Sb4[(4*bj+1)*17 + bi] = make_float4(o0.y,o1.y,o2.y,o3.y);
        Sb4[(4*bj+2)*17 + bi] = make_float4(o0.z,o1.z,o2.z,o3.z);
        Sb4[(4*bj+3)*17 + bi] = make_float4(o0.w,o1.w,o2.w,o3.w);
      }
    }
    __syncthreads();
    // c: invert
    gj8(Sb, T, colb, t);
    // d: rev + affine dnu
    if (t < 64) {
      float re_t = partA[t] + partA[64 + t] + partA[128 + t] - 1.0f;
      rev[t] = re_t;
      float rh = partB[t] + partB[64 + t] + partB[128 + t] + re_t;
      dnu[t] = matS_lds(Sb, rh, t);
    }
    __syncthreads();
    // e: affine direction + fused {step-min, mu-poly} reduce
    float dsa = 0.f, dla = 0.f;
    if (owner) {
      float atd = dot64_row(As4, dnu4, t);
      float dza = (top1 - atd) * wt;
      dsa = dza - rit;
      dla = g1 - Dt * dza;
      float r1 = dsa < 0.f ? -st / dsa : 1e10f;
      float r2 = dla < 0.f ? -lt / dla : 1e10f;
      float mn = fminf(r1, r2);
      float q0 = st * lt;                  // p2(a) = q0 + a q1 + a^2 q2
      float q1 = st * dla + dsa * lt;
      float q2 = dsa * dla;
#pragma unroll
      for (int off = 32; off > 0; off >>= 1) {
        mn = fminf(mn, __shfl_xor(mn, off, 64));
        q0 += __shfl_xor(q0, off, 64);
        q1 += __shfl_xor(q1, off, 64);
        q2 += __shfl_xor(q2, off, 64);
      }
      if (lane == 0) {
        red[wav] = mn; red[4+wav] = q0; red[8+wav] = q1; red[12+wav] = q2;
      }
    }
    __syncthreads();
    // f: sigma + corrector rhs operand
    float top2 = 0.f;
    if (owner) {
      const float a_aff = fminf(1.0f, 0.999f * fminf(fminf(red[0],red[1]), fminf(red[2],red[3])));
      const float S0 = red[4] + red[5] + red[6] + red[7];
      const float S1 = red[8] + red[9] + red[10] + red[11];
      const float S2 = red[12] + red[13] + red[14] + red[15];
      const float mu  = S0 * (1.0f / 256.0f);
      const float mua = (S0 + a_aff * S1 + a_aff * a_aff * S2) * (1.0f / 256.0f);
      float sig = mua / mu; sig = sig * sig * sig;
      const float smu = sig * mu;
      const float g2  = g1 + (smu - dsa * dla) / st;
      top2 = -rxt + g2;
      wtp[t] = top2 * wt;
    }
    __syncthreads();
    // g: corrector A@wtp partials (all 8 waves)
    {
      float accB = 0.f;
      for (int cc = 0; cc < 32; ++cc) {
        int c = (wav << 5) + cc;
        accB = fmaf(wtp[c], As[c * 64 + lane], accB);
      }
      partB2[t] = accB;
    }
    __syncthreads();
    // h: corrector dnu
    if (t < 64) {
      float rh = partB2[t] + partB2[64+t] + partB2[128+t] + partB2[192+t]
               + partB2[256+t] + partB2[320+t] + partB2[384+t] + partB2[448+t]
               + rev[t];
      dnu[t] = matS_lds(Sb, rh, t);
    }
    __syncthreads();
    // i: final direction + step reduce
    float ds2 = 0.f, dl2 = 0.f, dz2 = 0.f, atd2 = 0.f;
    if (owner) {
      atd2 = dot64_row(As4, dnu4, t);
      dz2 = (top2 - atd2) * wt;
      ds2 = dz2 - rit;
      dl2 = (top2 + rxt) - Dt * dz2;       // g2 = top2 + rxt
      float r1 = ds2 < 0.f ? -st / ds2 : 1e10f;
      float r2 = dl2 < 0.f ? -lt / dl2 : 1e10f;
      float mn = fminf(r1, r2);
#pragma unroll
      for (int off = 32; off > 0; off >>= 1) mn = fminf(mn, __shfl_xor(mn, off, 64));
      if (lane == 0) red[wav] = mn;
    }
    __syncthreads();
    // j: update + NEXT-iteration prep (nuA carry: dnu@A = atd2 already known)
    if (owner) {
      const float a = fminf(1.0f, 0.999f * fminf(fminf(red[0],red[1]), fminf(red[2],red[3])));
      zt += a * dz2;
      st = fmaxf(st + a * ds2, 1e-8f);
      lt = fmaxf(lt + a * dl2, 1e-8f);
      z[t] = zt;
      nuA = fmaf(a, atd2, nuA);            // (nu + a*dnu) @ A
      rxt = 0.1f * zt - hr - lt + nuA;
      rit = st - zt;
      Dt  = lt / st;
      wt  = 1.0f / (0.1f + Dt);
      g1  = -Dt * zt;
      top1 = -rxt + g1;
      wHd[t] = wt;
      wtp[t] = top1 * wt;
    }
    __syncthreads();
  }

  // ---- logits = z @ W2^T + b2 ; log_softmax ----
  if (t < 160) {
    int cls = t >> 4, pp = t & 15;
    float acc = 0.f;
#pragma unroll
    for (int e = 0; e < 16; ++e) {
      int c = (pp << 4) + e;
      acc = fmaf(z[c], W2[cls * 256 + c], acc);
    }
    partA[t] = acc;
  }
  __syncthreads();
  if (t < 10) {
    float s = b2[t];
#pragma unroll
    for (int pp = 0; pp < 16; ++pp) s += partA[(t << 4) + pp];
    red[t] = s;
  }
  __syncthreads();
  if (t == 0) {
    float mx = red[0];
#pragma unroll
    for (int c = 1; c < 10; ++c) mx = fmaxf(mx, red[c]);
    float se = 0.f;
#pragma unroll
    for (int c = 0; c < 10; ++c) se += expf(red[c] - mx);
    float lse = mx + logf(se);
    for (int c = 0; c < 10; ++c) out[b * 10 + c] = red[c] - lse;
  }
}

extern "C" void kernel_launch(void* const* d_in, const int* in_sizes, int n_in,
                              void* d_out, int out_size, void* d_ws, size_t ws_size,
                              hipStream_t stream) {
  (void)in_sizes; (void)n_in; (void)out_size; (void)d_ws; (void)ws_size;
  const float* x  = (const float*)d_in[0];
  const float* W1 = (const float*)d_in[1];
  const float* b1 = (const float*)d_in[2];
  const float* W2 = (const float*)d_in[3];
  const float* b2 = (const float*)d_in[4];
  const float* A  = (const float*)d_in[5];
  float* out = (float*)d_out;

  // floats: As 16384 + Sb 4352 + Pbuf 2176 + T 512 + colb 512 + (h,z,wHd,wtp)=4*256
  //         + partA 192 + partB 192 + partB2 512 + nu/rev/dnu 3*64 + red 16
  const size_t shmem = (16384 + 4352 + 2176 + 512 + 512 + 4*256 + 192 + 192 + 512 + 3*64 + 16)
                       * sizeof(float);   // 104256 B
  (void)hipFuncSetAttribute((const void*)optnet_kernel,
                            hipFuncAttributeMaxDynamicSharedMemorySize, (int)shmem);
  optnet_kernel<<<128, NTH, shmem, stream>>>(x, W1, b1, W2, b2, A, out);
}